// Round 25
// baseline (194.928 us; speedup 1.0000x reference)
//
#include <hip/hip_runtime.h>
#include <hip/hip_bf16.h>
#include <cstdint>

#define BB 4
#define TT 2048
#define CC 1024
#define HH 16
#define HS 64
#define MM (BB*TT)   // 8192

// scores computed in exp2 domain: fold 8 * log2(e) into Q once (QKV epilogue)
#define QSCALE 11.5415603629f

typedef _Float16 f16;
typedef _Float16 f16x8 __attribute__((ext_vector_type(8)));
typedef _Float16 f16x4 __attribute__((ext_vector_type(4)));
typedef float f32x4 __attribute__((ext_vector_type(4)));
typedef float f32x16 __attribute__((ext_vector_type(16)));

#define MFMA16(a,b,c) __builtin_amdgcn_mfma_f32_16x16x32_f16(a,b,c,0,0,0)
#define MFMA32(a,b,c) __builtin_amdgcn_mfma_f32_32x32x16_f16(a,b,c,0,0,0)

__device__ __forceinline__ void g2lds16(void* lds, const void* g) {
  __builtin_amdgcn_global_load_lds(
      (const __attribute__((address_space(1))) void*)g,
      (__attribute__((address_space(3))) void*)lds, 16, 0, 0);
}

__device__ __forceinline__ int pk2(float a, float b) {
  auto r = __builtin_amdgcn_cvt_pkrtz(a, b);   // __fp16 ext_vector(2)
  return __builtin_bit_cast(int, r);
}

union U8 { int4 i; f16x8 h; };

// ---------------- pre-pass: f32 -> f16 convert ----------------
__global__ __launch_bounds__(256) void cvt_kernel(const float* __restrict__ in,
                                                  f16* __restrict__ out, int n4) {
  int i = blockIdx.x * blockDim.x + threadIdx.x;
  if (i < n4) {
    float4 v = ((const float4*)in)[i];
    f16x4 o;
    o[0] = (f16)v.x; o[1] = (f16)v.y; o[2] = (f16)v.z; o[3] = (f16)v.w;
    ((f16x4*)out)[i] = o;
  }
}

// ---------------- pre-pass: transpose + convert: in[K][N] f32 -> out[N][K] f16
__global__ __launch_bounds__(256) void transpose_cvt(const float* __restrict__ in,
                                                     f16* __restrict__ out,
                                                     int K, int N) {
  __shared__ float tile[32][33];
  int n0 = blockIdx.x * 32, k0 = blockIdx.y * 32;
  int tx = threadIdx.x, ty = threadIdx.y;
  #pragma unroll
  for (int i = 0; i < 32; i += 8)
    tile[ty + i][tx] = in[(size_t)(k0 + ty + i) * N + n0 + tx];
  __syncthreads();
  #pragma unroll
  for (int i = 0; i < 32; i += 8)
    out[(size_t)(n0 + ty + i) * K + k0 + tx] = (f16)tile[tx][ty + i];
}

// ---------------- GEMM v8: 128x128 tile, 4 waves x 64x64 (m97 geometry) ----
// Same proven schedule as round 16 (dbuf + counted vmcnt + T2 swizzle +
// setprio) but wave tile 64x64 (acc[4][4]): LDS-read per FLOP drops 1.5x
// (21.8 -> 32.8 FLOP/B), balancing the LDS pipe against the MFMA pipe.
// 256 thr/block; staging = 8 g2lds/thread/tile -> counted vmcnt(8).
__device__ __forceinline__ void gstage(const f16* __restrict__ A,
                                       const f16* __restrict__ Bt,
                                       f16* as, f16* bs,
                                       int row0, int col0, int kt, int t) {
  const int K = 1024;
  #pragma unroll
  for (int i = 0; i < 4; ++i) {
    int off = i * 4096 + t * 16;        // byte offset in 16KB tile
    int row = off >> 7;                 // 128B per row
    int cbB = off & 127;
    int scb = cbB ^ ((row & 7) << 4);   // pre-swizzled source byte col
    g2lds16((char*)as + off, (const char*)(A  + (size_t)(row0 + row) * K + kt) + scb);
    g2lds16((char*)bs + off, (const char*)(Bt + (size_t)(col0 + row) * K + kt) + scb);
  }
}

template<int EPI>
__global__ __launch_bounds__(256) void gemm_bt(const f16* __restrict__ A,
                                               const f16* __restrict__ Bt,
                                               f16* __restrict__ qT,
                                               f16* __restrict__ kT,
                                               f16* __restrict__ vT,
                                               const float* __restrict__ bias,
                                               float* __restrict__ outF) {
  const int K = 1024;
  __shared__ f16 As[2][128 * 64];
  __shared__ f16 Bs[2][128 * 64];
  const int t = threadIdx.x;
  const int l = t & 63, w = t >> 6;     // 4 waves
  const int lr = l & 15, lh = l >> 4;
  const int row0 = blockIdx.y * 128, col0 = blockIdx.x * 128;
  const int wr = (w >> 1) * 64, wc = (w & 1) * 64;
  const int sx = (lr & 7) << 4;         // read-side swizzle (row&7 == lr&7)

  f32x4 acc[4][4] = {};

  gstage(A, Bt, As[0], Bs[0], row0, col0, 0, t);
  int buf = 0;
  for (int kt = 0; kt < K; kt += 64) {
    asm volatile("" ::: "memory");
    const bool pf = (kt + 64) < K;           // wave-uniform
    if (pf) gstage(A, Bt, As[buf ^ 1], Bs[buf ^ 1], row0, col0, kt + 64, t);
    // wait for THIS tile's 8 loads (oldest); keep next tile's 8 in flight
    if (pf) asm volatile("s_waitcnt vmcnt(8)" ::: "memory");
    else    asm volatile("s_waitcnt vmcnt(0)" ::: "memory");
    __builtin_amdgcn_sched_barrier(0);
    __builtin_amdgcn_s_barrier();            // all waves' tile-kt loads done
    const char* as = (const char*)As[buf];
    const char* bs = (const char*)Bs[buf];
    __builtin_amdgcn_s_setprio(1);
    #pragma unroll
    for (int kk = 0; kk < 64; kk += 32) {
      f16x8 af[4], bfr[4];
      #pragma unroll
      for (int m = 0; m < 4; ++m)
        af[m]  = *(const f16x8*)(as + (wr + m * 16 + lr) * 128
                                    + ((kk * 2 + lh * 16) ^ sx));
      #pragma unroll
      for (int n = 0; n < 4; ++n)
        bfr[n] = *(const f16x8*)(bs + (wc + n * 16 + lr) * 128
                                    + ((kk * 2 + lh * 16) ^ sx));
      #pragma unroll
      for (int m = 0; m < 4; ++m)
        #pragma unroll
        for (int n = 0; n < 4; ++n)
          acc[m][n] = MFMA16(af[m], bfr[n], acc[m][n]);
    }
    __builtin_amdgcn_s_setprio(0);
    __builtin_amdgcn_sched_barrier(0);
    __builtin_amdgcn_s_barrier();            // readers done before buf overwrite
    buf ^= 1;
  }

  #pragma unroll
  for (int m = 0; m < 4; ++m) {
    #pragma unroll
    for (int n = 0; n < 4; ++n) {
      #pragma unroll
      for (int j = 0; j < 4; ++j) {
        float val = acc[m][n][j];
        int gr = row0 + wr + m * 16 + lh * 4 + j;   // M index
        int gc = col0 + wc + n * 16 + lr;           // N index
        if (EPI == 0) {
          int which = gc >> 10;          // 0=q 1=k 2=v
          int c = gc & 1023;
          int h = c >> 6, d = c & 63;
          int b = gr >> 11, tt = gr & 2047;
          size_t bh = (size_t)(b * HH + h);
          if (which == 0)      qT[(bh * TT + tt) * HS + d] = (f16)(val * QSCALE);
          else if (which == 1) kT[(bh * TT + tt) * HS + d] = (f16)val;
          else                 vT[(bh * HS + d) * TT + tt] = (f16)val;
        } else {
          outF[(size_t)gr * CC + gc] = val + bias[gc];
        }
      }
    }
  }
}

// ---------------- flash attention v9: step-split wave-sets (2x TLP) --------
template<bool MASKED>
__device__ __forceinline__ void step32L(
    int kglob, int qa, int l31, int hi,
    const f16* __restrict__ ks, const f16* __restrict__ vs, int kbs,
    const f16x8 (&qf)[4],
    float& m, f32x4& lv, f32x16& oA, f32x16& oB) {
  const int sx = (l31 & 7) << 4;               // row-XOR swizzle (row&7 == l31&7)
  const char* krow = (const char*)(ks + (kbs + l31) * 64);
  f32x16 sa = {}, sb = {};
  {
    f16x8 kf0 = *(const f16x8*)(krow + ((0 * 32 + hi * 16) ^ sx));
    f16x8 kf1 = *(const f16x8*)(krow + ((1 * 32 + hi * 16) ^ sx));
    f16x8 kf2 = *(const f16x8*)(krow + ((2 * 32 + hi * 16) ^ sx));
    f16x8 kf3 = *(const f16x8*)(krow + ((3 * 32 + hi * 16) ^ sx));
    sa = MFMA32(kf0, qf[0], sa);
    sb = MFMA32(kf2, qf[2], sb);
    sa = MFMA32(kf1, qf[1], sa);
    sb = MFMA32(kf3, qf[3], sb);
  }
  float p[16];
  #pragma unroll
  for (int r = 0; r < 16; ++r) {
    float sv = sa[r] + sb[r];
    if (MASKED) {
      int k = kglob + (r & 3) + 8 * (r >> 2) + 4 * hi;
      p[r] = (k <= qa) ? sv : -INFINITY;
    } else p[r] = sv;
  }
  float t0 = fmaxf(fmaxf(p[0], p[1]), fmaxf(p[2], p[3]));
  float t1 = fmaxf(fmaxf(p[4], p[5]), fmaxf(p[6], p[7]));
  float t2 = fmaxf(fmaxf(p[8], p[9]), fmaxf(p[10], p[11]));
  float t3 = fmaxf(fmaxf(p[12], p[13]), fmaxf(p[14], p[15]));
  float mx = fmaxf(fmaxf(t0, t1), fmaxf(t2, t3));
  if (__any(mx > m + 14.0f)) {                 // rare rescale path
    mx = fmaxf(mx, __shfl_xor(mx, 32));
    float mn = fmaxf(m, mx);
    float corr = __builtin_amdgcn_exp2f(m - mn);
    m = mn;
    #pragma unroll
    for (int r = 0; r < 4; ++r) lv[r] *= corr;
    #pragma unroll
    for (int r = 0; r < 16; ++r) { oA[r] *= corr; oB[r] *= corr; }
  }
  #pragma unroll
  for (int r = 0; r < 16; ++r) {
    p[r] = __builtin_amdgcn_exp2f(p[r] - m);   // bounded by 2^14 (f16-safe)
    lv[r & 3] += p[r];
  }
  // P -> f16 pairs; half-exchange via v_permlane32_swap_b32 (VALU pipe)
  int pkv[8];
  #pragma unroll
  for (int j = 0; j < 8; ++j) pkv[j] = pk2(p[2 * j], p[2 * j + 1]);
  int e0 = pkv[0], e2 = pkv[2];
  asm("v_permlane32_swap_b32 %0, %1" : "+v"(e0), "+v"(e2));
  int e1 = pkv[1], e3 = pkv[3];
  asm("v_permlane32_swap_b32 %0, %1" : "+v"(e1), "+v"(e3));
  int f0 = pkv[4], f2 = pkv[6];
  asm("v_permlane32_swap_b32 %0, %1" : "+v"(f0), "+v"(f2));
  int f1 = pkv[5], f3 = pkv[7];
  asm("v_permlane32_swap_b32 %0, %1" : "+v"(f1), "+v"(f3));
  U8 b0, b1;
  b0.i = (int4){ e0, e1, e2, e3 };
  b1.i = (int4){ f0, f1, f2, f3 };
  const char* vrow0 = (const char*)(vs + l31 * 64);
  const char* vrow1 = (const char*)(vs + (l31 + 32) * 64);
  const int kc0 = (kbs * 2 + hi * 16) ^ sx;
  const int kc1 = (kbs * 2 + hi * 16 + 32) ^ sx;
  f16x8 v00 = *(const f16x8*)(vrow0 + kc0);
  f16x8 v01 = *(const f16x8*)(vrow0 + kc1);
  f16x8 v10 = *(const f16x8*)(vrow1 + kc0);
  f16x8 v11 = *(const f16x8*)(vrow1 + kc1);
  oA = MFMA32(v00, b0.h, oA);
  oA = MFMA32(v01, b1.h, oA);
  oB = MFMA32(v10, b0.h, oB);
  oB = MFMA32(v11, b1.h, oB);
}

struct SmemU {
  union {
    f16 kv[2][2][4096];        // [buf][K=0/V=1][elem] = 32 KB staging
    float om[4][64][32];       // 32 KB merge-O overlay (staging drained)
  };
  float mls[4][64][2];         // 2 KB merge (m, lsum)
};

__device__ __forceinline__ void stage8(const f16* __restrict__ Kb,
                                       const f16* __restrict__ Vb,
                                       f16* ks, f16* vs,
                                       int kb, int w, int l) {
  int off = w * 1024 + l * 16;    // 8 waves cover the 8 KB tile
  int row = off >> 7;
  int cb  = off & 127;
  int scb = cb ^ ((row & 7) << 4);
  g2lds16((char*)ks + off, (const char*)(Kb + (size_t)(kb + row) * HS) + scb);
  g2lds16((char*)vs + off, (const char*)(Vb + (size_t)row * TT + kb) + scb);
}

// grid (64 bh, 8 pairs). Block: q-block (15-pr) then (pr) -> uniform 34 units.
__global__ __launch_bounds__(512) void attn_kernel(const f16* __restrict__ qT,
                                                   const f16* __restrict__ kT,
                                                   const f16* __restrict__ vT,
                                                   f16* __restrict__ aout) {
  const int bh = blockIdx.x;        // x-fastest: same-bh blocks on XCD bh%8
  const int pr = blockIdx.y;        // 0..7
  const int t = threadIdx.x, l = t & 63, w = t >> 6;   // w 0..7
  const int ws = w & 3;             // q-subtile (32 rows) within 128
  const int kh = w >> 2;            // step-set: 0 -> kb, 1 -> kb+32
  const int l31 = l & 31, hi = l >> 5;
  const f16* __restrict__ Qb = qT + (size_t)bh * TT * HS;
  const f16* __restrict__ Kb = kT + (size_t)bh * TT * HS;
  const f16* __restrict__ Vb = vT + (size_t)bh * HS * TT;
  const int b = bh >> 4, h = bh & 15;

  __shared__ SmemU S;
  const int swm = (l & 7) << 2;     // merge-O float4 XOR swizzle

  #pragma unroll
  for (int ph = 0; ph < 2; ++ph) {
    const int qb = ph ? pr : (15 - pr);   // heavy phase first
    const int q0w = qb * 128 + ws * 32;
    const int qa = q0w + l31;

    f16x8 qf[4];
    #pragma unroll
    for (int j = 0; j < 4; ++j)
      qf[j] = *(const f16x8*)&Qb[(size_t)qa * HS + 16 * j + hi * 8];

    float m = -INFINITY;
    f32x4 lv = {};
    f32x16 oA = {}, oB = {};

    const int nt = 2 * qb + 2;
    stage8(Kb, Vb, S.kv[0][0], S.kv[0][1], 0, w, l);
    __syncthreads();
    int buf = 0;
    for (int ti = 0; ti < nt; ++ti) {
      if (ti + 1 < nt)
        stage8(Kb, Vb, S.kv[buf ^ 1][0], S.kv[buf ^ 1][1], (ti + 1) * 64, w, l);
      const int kb = ti * 64;
      const f16* ks = S.kv[buf][0];
      const f16* vs = S.kv[buf][1];
      if (kh == 0) {                           // wave-uniform branches
        if (kb < q0w)
          step32L<false>(kb, qa, l31, hi, ks, vs, 0, qf, m, lv, oA, oB);
        else if (kb == q0w)
          step32L<true >(kb, qa, l31, hi, ks, vs, 0, qf, m, lv, oA, oB);
      } else {
        if (kb + 32 < q0w)
          step32L<false>(kb + 32, qa, l31, hi, ks, vs, 32, qf, m, lv, oA, oB);
        else if (kb + 32 == q0w)
          step32L<true >(kb + 32, qa, l31, hi, ks, vs, 32, qf, m, lv, oA, oB);
      }
      __syncthreads();
      buf ^= 1;
    }

    float lsum = (lv[0] + lv[1]) + (lv[2] + lv[3]);
    lsum += __shfl_xor(lsum, 32);

    // ---- exact 2-way merge across step-sets (w and w+4 share q-rows) ----
    if (kh == 1) {
      #pragma unroll
      for (int rb = 0; rb < 4; ++rb) {
        f32x4 va = { oA[rb*4+0], oA[rb*4+1], oA[rb*4+2], oA[rb*4+3] };
        f32x4 vb = { oB[rb*4+0], oB[rb*4+1], oB[rb*4+2], oB[rb*4+3] };
        *(f32x4*)&S.om[ws][l][(rb * 4) ^ swm]        = va;
        *(f32x4*)&S.om[ws][l][((4 + rb) * 4) ^ swm]  = vb;
      }
      S.mls[ws][l][0] = m;
      S.mls[ws][l][1] = lsum;
    }
    __syncthreads();
    if (kh == 0) {
      float mB = S.mls[ws][l][0], lB = S.mls[ws][l][1];
      float mS = fmaxf(fmaxf(m, mB), -3.0e38f);   // finite guard (empty set)
      float cA = __builtin_amdgcn_exp2f(m - mS);
      float cB = __builtin_amdgcn_exp2f(mB - mS);
      float li = 1.0f / (lsum * cA + lB * cB);
      float sA = cA * li, sB = cB * li;
      f16* orow = aout + (size_t)(b * TT + qa) * CC + h * HS;
      #pragma unroll
      for (int rq = 0; rq < 4; ++rq) {
        f32x4 obl = *(const f32x4*)&S.om[ws][l][(rq * 4) ^ swm];
        f32x4 obh = *(const f32x4*)&S.om[ws][l][((4 + rq) * 4) ^ swm];
        f16x4 o4a, o4b;
        #pragma unroll
        for (int j = 0; j < 4; ++j) {
          int r = rq * 4 + j;
          o4a[j] = (f16)(oA[r] * sA + obl[j] * sB);
          o4b[j] = (f16)(oB[r] * sA + obh[j] * sB);
        }
        int dA = 8 * rq + 4 * hi;
        *(f16x4*)&orow[dA]      = o4a;
        *(f16x4*)&orow[32 + dA] = o4b;
      }
    }
    __syncthreads();   // om overlays staging: next phase must wait
  }
}

// ---------------- launch ----------------
extern "C" void kernel_launch(void* const* d_in, const int* in_sizes, int n_in,
                              void* d_out, int out_size, void* d_ws, size_t ws_size,
                              hipStream_t stream) {
  const float* x      = (const float*)d_in[0];
  const float* w_kqv  = (const float*)d_in[1];
  const float* w_proj = (const float*)d_in[2];
  const float* b_proj = (const float*)d_in[3];
  float* out = (float*)d_out;

  char* ws = (char*)d_ws;
  f16* xb    = (f16*)(ws);                       // 16,777,216 B
  f16* wkqvT = (f16*)(ws + 16777216);            //  6,291,456
  f16* wpT   = (f16*)(ws + 23068672);            //  2,097,152
  f16* qT    = (f16*)(ws + 25165824);            // 16,777,216
  f16* kT    = (f16*)(ws + 41943040);            // 16,777,216
  f16* vT    = (f16*)(ws + 58720256);            // 16,777,216
  f16* aout  = (f16*)(ws + 75497472);            // 16,777,216  -> ~92.3 MB

  cvt_kernel<<<8192, 256, 0, stream>>>(x, xb, (MM * CC) / 4);
  transpose_cvt<<<dim3(3 * CC / 32, CC / 32), dim3(32, 8), 0, stream>>>(w_kqv, wkqvT, CC, 3 * CC);
  transpose_cvt<<<dim3(CC / 32, CC / 32), dim3(32, 8), 0, stream>>>(w_proj, wpT, CC, CC);

  gemm_bt<0><<<dim3(3 * CC / 128, MM / 128), 256, 0, stream>>>(xb, wkqvT, qT, kT, vT, nullptr, nullptr);

  attn_kernel<<<dim3(BB * HH, 8), 512, 0, stream>>>(qT, kT, vT, aout);

  gemm_bt<1><<<dim3(CC / 128, MM / 128), 256, 0, stream>>>(aout, wpT, nullptr, nullptr, nullptr, b_proj, out);
}

// Round 26
// 194.290 us; speedup vs baseline: 1.0033x; 1.0033x over previous
//
#include <hip/hip_runtime.h>
#include <hip/hip_bf16.h>
#include <cstdint>

#define BB 4
#define TT 2048
#define CC 1024
#define HH 16
#define HS 64
#define MM (BB*TT)   // 8192

// scores computed in exp2 domain: fold 8 * log2(e) into Q once (QKV epilogue)
#define QSCALE 11.5415603629f

typedef _Float16 f16;
typedef _Float16 f16x8 __attribute__((ext_vector_type(8)));
typedef _Float16 f16x4 __attribute__((ext_vector_type(4)));
typedef float f32x4 __attribute__((ext_vector_type(4)));
typedef float f32x16 __attribute__((ext_vector_type(16)));

#define MFMA16(a,b,c) __builtin_amdgcn_mfma_f32_16x16x32_f16(a,b,c,0,0,0)
#define MFMA32(a,b,c) __builtin_amdgcn_mfma_f32_32x32x16_f16(a,b,c,0,0,0)

__device__ __forceinline__ void g2lds16(void* lds, const void* g) {
  __builtin_amdgcn_global_load_lds(
      (const __attribute__((address_space(1))) void*)g,
      (__attribute__((address_space(3))) void*)lds, 16, 0, 0);
}

__device__ __forceinline__ int pk2(float a, float b) {
  auto r = __builtin_amdgcn_cvt_pkrtz(a, b);   // __fp16 ext_vector(2)
  return __builtin_bit_cast(int, r);
}

union U8 { int4 i; f16x8 h; };

// ---------------- pre-pass: f32 -> f16 convert ----------------
__global__ __launch_bounds__(256) void cvt_kernel(const float* __restrict__ in,
                                                  f16* __restrict__ out, int n4) {
  int i = blockIdx.x * blockDim.x + threadIdx.x;
  if (i < n4) {
    float4 v = ((const float4*)in)[i];
    f16x4 o;
    o[0] = (f16)v.x; o[1] = (f16)v.y; o[2] = (f16)v.z; o[3] = (f16)v.w;
    ((f16x4*)out)[i] = o;
  }
}

// ---------------- pre-pass: transpose + convert: in[K][N] f32 -> out[N][K] f16
__global__ __launch_bounds__(256) void transpose_cvt(const float* __restrict__ in,
                                                     f16* __restrict__ out,
                                                     int K, int N) {
  __shared__ float tile[32][33];
  int n0 = blockIdx.x * 32, k0 = blockIdx.y * 32;
  int tx = threadIdx.x, ty = threadIdx.y;
  #pragma unroll
  for (int i = 0; i < 32; i += 8)
    tile[ty + i][tx] = in[(size_t)(k0 + ty + i) * N + n0 + tx];
  __syncthreads();
  #pragma unroll
  for (int i = 0; i < 32; i += 8)
    out[(size_t)(n0 + ty + i) * K + k0 + tx] = (f16)tile[tx][ty + i];
}

// ---------------- GEMM v9: exact m97 structure ----------------
// 128x128 tile, 4 waves x 64x64 (acc[4][4]), SINGLE 32KB LDS buffer,
// plain __syncthreads (compiler-drained vmcnt). 5 blocks/CU = 20 waves/CU:
// inter-block wave overlap hides the stage drain (m114/m99 evidence —
// explicit dbuf halves residency and is net worse). T2 swizzle + setprio kept.
__device__ __forceinline__ void gstage(const f16* __restrict__ A,
                                       const f16* __restrict__ Bt,
                                       f16* as, f16* bs,
                                       int row0, int col0, int kt, int t) {
  const int K = 1024;
  #pragma unroll
  for (int i = 0; i < 4; ++i) {
    int off = i * 4096 + t * 16;        // byte offset in 16KB tile
    int row = off >> 7;                 // 128B per row
    int cbB = off & 127;
    int scb = cbB ^ ((row & 7) << 4);   // pre-swizzled source byte col
    g2lds16((char*)as + off, (const char*)(A  + (size_t)(row0 + row) * K + kt) + scb);
    g2lds16((char*)bs + off, (const char*)(Bt + (size_t)(col0 + row) * K + kt) + scb);
  }
}

template<int EPI>
__global__ __launch_bounds__(256) void gemm_bt(const f16* __restrict__ A,
                                               const f16* __restrict__ Bt,
                                               f16* __restrict__ qT,
                                               f16* __restrict__ kT,
                                               f16* __restrict__ vT,
                                               const float* __restrict__ bias,
                                               float* __restrict__ outF) {
  const int K = 1024;
  __shared__ f16 As[128 * 64];
  __shared__ f16 Bs[128 * 64];
  const int t = threadIdx.x;
  const int l = t & 63, w = t >> 6;     // 4 waves
  const int lr = l & 15, lh = l >> 4;
  const int row0 = blockIdx.y * 128, col0 = blockIdx.x * 128;
  const int wr = (w >> 1) * 64, wc = (w & 1) * 64;
  const int sx = (lr & 7) << 4;         // read-side swizzle (row&7 == lr&7)

  f32x4 acc[4][4] = {};

  for (int kt = 0; kt < K; kt += 64) {
    gstage(A, Bt, As, Bs, row0, col0, kt, t);
    __syncthreads();                     // drains vmcnt: tile ready
    const char* as = (const char*)As;
    const char* bs = (const char*)Bs;
    __builtin_amdgcn_s_setprio(1);
    #pragma unroll
    for (int kk = 0; kk < 64; kk += 32) {
      f16x8 af[4], bfr[4];
      #pragma unroll
      for (int m = 0; m < 4; ++m)
        af[m]  = *(const f16x8*)(as + (wr + m * 16 + lr) * 128
                                    + ((kk * 2 + lh * 16) ^ sx));
      #pragma unroll
      for (int n = 0; n < 4; ++n)
        bfr[n] = *(const f16x8*)(bs + (wc + n * 16 + lr) * 128
                                    + ((kk * 2 + lh * 16) ^ sx));
      #pragma unroll
      for (int m = 0; m < 4; ++m)
        #pragma unroll
        for (int n = 0; n < 4; ++n)
          acc[m][n] = MFMA16(af[m], bfr[n], acc[m][n]);
    }
    __builtin_amdgcn_s_setprio(0);
    __syncthreads();                     // readers done before next overwrite
  }

  #pragma unroll
  for (int m = 0; m < 4; ++m) {
    #pragma unroll
    for (int n = 0; n < 4; ++n) {
      #pragma unroll
      for (int j = 0; j < 4; ++j) {
        float val = acc[m][n][j];
        int gr = row0 + wr + m * 16 + lh * 4 + j;   // M index
        int gc = col0 + wc + n * 16 + lr;           // N index
        if (EPI == 0) {
          int which = gc >> 10;          // 0=q 1=k 2=v
          int c = gc & 1023;
          int h = c >> 6, d = c & 63;
          int b = gr >> 11, tt = gr & 2047;
          size_t bh = (size_t)(b * HH + h);
          if (which == 0)      qT[(bh * TT + tt) * HS + d] = (f16)(val * QSCALE);
          else if (which == 1) kT[(bh * TT + tt) * HS + d] = (f16)val;
          else                 vT[(bh * HS + d) * TT + tt] = (f16)val;
        } else {
          outF[(size_t)gr * CC + gc] = val + bias[gc];
        }
      }
    }
  }
}

// ---------------- flash attention v9: step-split wave-sets (2x TLP) --------
template<bool MASKED>
__device__ __forceinline__ void step32L(
    int kglob, int qa, int l31, int hi,
    const f16* __restrict__ ks, const f16* __restrict__ vs, int kbs,
    const f16x8 (&qf)[4],
    float& m, f32x4& lv, f32x16& oA, f32x16& oB) {
  const int sx = (l31 & 7) << 4;               // row-XOR swizzle (row&7 == l31&7)
  const char* krow = (const char*)(ks + (kbs + l31) * 64);
  f32x16 sa = {}, sb = {};
  {
    f16x8 kf0 = *(const f16x8*)(krow + ((0 * 32 + hi * 16) ^ sx));
    f16x8 kf1 = *(const f16x8*)(krow + ((1 * 32 + hi * 16) ^ sx));
    f16x8 kf2 = *(const f16x8*)(krow + ((2 * 32 + hi * 16) ^ sx));
    f16x8 kf3 = *(const f16x8*)(krow + ((3 * 32 + hi * 16) ^ sx));
    sa = MFMA32(kf0, qf[0], sa);
    sb = MFMA32(kf2, qf[2], sb);
    sa = MFMA32(kf1, qf[1], sa);
    sb = MFMA32(kf3, qf[3], sb);
  }
  float p[16];
  #pragma unroll
  for (int r = 0; r < 16; ++r) {
    float sv = sa[r] + sb[r];
    if (MASKED) {
      int k = kglob + (r & 3) + 8 * (r >> 2) + 4 * hi;
      p[r] = (k <= qa) ? sv : -INFINITY;
    } else p[r] = sv;
  }
  float t0 = fmaxf(fmaxf(p[0], p[1]), fmaxf(p[2], p[3]));
  float t1 = fmaxf(fmaxf(p[4], p[5]), fmaxf(p[6], p[7]));
  float t2 = fmaxf(fmaxf(p[8], p[9]), fmaxf(p[10], p[11]));
  float t3 = fmaxf(fmaxf(p[12], p[13]), fmaxf(p[14], p[15]));
  float mx = fmaxf(fmaxf(t0, t1), fmaxf(t2, t3));
  if (__any(mx > m + 14.0f)) {                 // rare rescale path
    mx = fmaxf(mx, __shfl_xor(mx, 32));
    float mn = fmaxf(m, mx);
    float corr = __builtin_amdgcn_exp2f(m - mn);
    m = mn;
    #pragma unroll
    for (int r = 0; r < 4; ++r) lv[r] *= corr;
    #pragma unroll
    for (int r = 0; r < 16; ++r) { oA[r] *= corr; oB[r] *= corr; }
  }
  #pragma unroll
  for (int r = 0; r < 16; ++r) {
    p[r] = __builtin_amdgcn_exp2f(p[r] - m);   // bounded by 2^14 (f16-safe)
    lv[r & 3] += p[r];
  }
  // P -> f16 pairs; half-exchange via v_permlane32_swap_b32 (VALU pipe)
  int pkv[8];
  #pragma unroll
  for (int j = 0; j < 8; ++j) pkv[j] = pk2(p[2 * j], p[2 * j + 1]);
  int e0 = pkv[0], e2 = pkv[2];
  asm("v_permlane32_swap_b32 %0, %1" : "+v"(e0), "+v"(e2));
  int e1 = pkv[1], e3 = pkv[3];
  asm("v_permlane32_swap_b32 %0, %1" : "+v"(e1), "+v"(e3));
  int f0 = pkv[4], f2 = pkv[6];
  asm("v_permlane32_swap_b32 %0, %1" : "+v"(f0), "+v"(f2));
  int f1 = pkv[5], f3 = pkv[7];
  asm("v_permlane32_swap_b32 %0, %1" : "+v"(f1), "+v"(f3));
  U8 b0, b1;
  b0.i = (int4){ e0, e1, e2, e3 };
  b1.i = (int4){ f0, f1, f2, f3 };
  const char* vrow0 = (const char*)(vs + l31 * 64);
  const char* vrow1 = (const char*)(vs + (l31 + 32) * 64);
  const int kc0 = (kbs * 2 + hi * 16) ^ sx;
  const int kc1 = (kbs * 2 + hi * 16 + 32) ^ sx;
  f16x8 v00 = *(const f16x8*)(vrow0 + kc0);
  f16x8 v01 = *(const f16x8*)(vrow0 + kc1);
  f16x8 v10 = *(const f16x8*)(vrow1 + kc0);
  f16x8 v11 = *(const f16x8*)(vrow1 + kc1);
  oA = MFMA32(v00, b0.h, oA);
  oA = MFMA32(v01, b1.h, oA);
  oB = MFMA32(v10, b0.h, oB);
  oB = MFMA32(v11, b1.h, oB);
}

struct SmemU {
  union {
    f16 kv[2][2][4096];        // [buf][K=0/V=1][elem] = 32 KB staging
    float om[4][64][32];       // 32 KB merge-O overlay (staging drained)
  };
  float mls[4][64][2];         // 2 KB merge (m, lsum)
};

__device__ __forceinline__ void stage8(const f16* __restrict__ Kb,
                                       const f16* __restrict__ Vb,
                                       f16* ks, f16* vs,
                                       int kb, int w, int l) {
  int off = w * 1024 + l * 16;    // 8 waves cover the 8 KB tile
  int row = off >> 7;
  int cb  = off & 127;
  int scb = cb ^ ((row & 7) << 4);
  g2lds16((char*)ks + off, (const char*)(Kb + (size_t)(kb + row) * HS) + scb);
  g2lds16((char*)vs + off, (const char*)(Vb + (size_t)row * TT + kb) + scb);
}

// grid (64 bh, 8 pairs). Block: q-block (15-pr) then (pr) -> uniform 34 units.
__global__ __launch_bounds__(512) void attn_kernel(const f16* __restrict__ qT,
                                                   const f16* __restrict__ kT,
                                                   const f16* __restrict__ vT,
                                                   f16* __restrict__ aout) {
  const int bh = blockIdx.x;        // x-fastest: same-bh blocks on XCD bh%8
  const int pr = blockIdx.y;        // 0..7
  const int t = threadIdx.x, l = t & 63, w = t >> 6;   // w 0..7
  const int ws = w & 3;             // q-subtile (32 rows) within 128
  const int kh = w >> 2;            // step-set: 0 -> kb, 1 -> kb+32
  const int l31 = l & 31, hi = l >> 5;
  const f16* __restrict__ Qb = qT + (size_t)bh * TT * HS;
  const f16* __restrict__ Kb = kT + (size_t)bh * TT * HS;
  const f16* __restrict__ Vb = vT + (size_t)bh * HS * TT;
  const int b = bh >> 4, h = bh & 15;

  __shared__ SmemU S;
  const int swm = (l & 7) << 2;     // merge-O float4 XOR swizzle

  #pragma unroll
  for (int ph = 0; ph < 2; ++ph) {
    const int qb = ph ? pr : (15 - pr);   // heavy phase first
    const int q0w = qb * 128 + ws * 32;
    const int qa = q0w + l31;

    f16x8 qf[4];
    #pragma unroll
    for (int j = 0; j < 4; ++j)
      qf[j] = *(const f16x8*)&Qb[(size_t)qa * HS + 16 * j + hi * 8];

    float m = -INFINITY;
    f32x4 lv = {};
    f32x16 oA = {}, oB = {};

    const int nt = 2 * qb + 2;
    stage8(Kb, Vb, S.kv[0][0], S.kv[0][1], 0, w, l);
    __syncthreads();
    int buf = 0;
    for (int ti = 0; ti < nt; ++ti) {
      if (ti + 1 < nt)
        stage8(Kb, Vb, S.kv[buf ^ 1][0], S.kv[buf ^ 1][1], (ti + 1) * 64, w, l);
      const int kb = ti * 64;
      const f16* ks = S.kv[buf][0];
      const f16* vs = S.kv[buf][1];
      if (kh == 0) {                           // wave-uniform branches
        if (kb < q0w)
          step32L<false>(kb, qa, l31, hi, ks, vs, 0, qf, m, lv, oA, oB);
        else if (kb == q0w)
          step32L<true >(kb, qa, l31, hi, ks, vs, 0, qf, m, lv, oA, oB);
      } else {
        if (kb + 32 < q0w)
          step32L<false>(kb + 32, qa, l31, hi, ks, vs, 32, qf, m, lv, oA, oB);
        else if (kb + 32 == q0w)
          step32L<true >(kb + 32, qa, l31, hi, ks, vs, 32, qf, m, lv, oA, oB);
      }
      __syncthreads();
      buf ^= 1;
    }

    float lsum = (lv[0] + lv[1]) + (lv[2] + lv[3]);
    lsum += __shfl_xor(lsum, 32);

    // ---- exact 2-way merge across step-sets (w and w+4 share q-rows) ----
    if (kh == 1) {
      #pragma unroll
      for (int rb = 0; rb < 4; ++rb) {
        f32x4 va = { oA[rb*4+0], oA[rb*4+1], oA[rb*4+2], oA[rb*4+3] };
        f32x4 vb = { oB[rb*4+0], oB[rb*4+1], oB[rb*4+2], oB[rb*4+3] };
        *(f32x4*)&S.om[ws][l][(rb * 4) ^ swm]        = va;
        *(f32x4*)&S.om[ws][l][((4 + rb) * 4) ^ swm]  = vb;
      }
      S.mls[ws][l][0] = m;
      S.mls[ws][l][1] = lsum;
    }
    __syncthreads();
    if (kh == 0) {
      float mB = S.mls[ws][l][0], lB = S.mls[ws][l][1];
      float mS = fmaxf(fmaxf(m, mB), -3.0e38f);   // finite guard (empty set)
      float cA = __builtin_amdgcn_exp2f(m - mS);
      float cB = __builtin_amdgcn_exp2f(mB - mS);
      float li = 1.0f / (lsum * cA + lB * cB);
      float sA = cA * li, sB = cB * li;
      f16* orow = aout + (size_t)(b * TT + qa) * CC + h * HS;
      #pragma unroll
      for (int rq = 0; rq < 4; ++rq) {
        f32x4 obl = *(const f32x4*)&S.om[ws][l][(rq * 4) ^ swm];
        f32x4 obh = *(const f32x4*)&S.om[ws][l][((4 + rq) * 4) ^ swm];
        f16x4 o4a, o4b;
        #pragma unroll
        for (int j = 0; j < 4; ++j) {
          int r = rq * 4 + j;
          o4a[j] = (f16)(oA[r] * sA + obl[j] * sB);
          o4b[j] = (f16)(oB[r] * sA + obh[j] * sB);
        }
        int dA = 8 * rq + 4 * hi;
        *(f16x4*)&orow[dA]      = o4a;
        *(f16x4*)&orow[32 + dA] = o4b;
      }
    }
    __syncthreads();   // om overlays staging: next phase must wait
  }
}

// ---------------- launch ----------------
extern "C" void kernel_launch(void* const* d_in, const int* in_sizes, int n_in,
                              void* d_out, int out_size, void* d_ws, size_t ws_size,
                              hipStream_t stream) {
  const float* x      = (const float*)d_in[0];
  const float* w_kqv  = (const float*)d_in[1];
  const float* w_proj = (const float*)d_in[2];
  const float* b_proj = (const float*)d_in[3];
  float* out = (float*)d_out;

  char* ws = (char*)d_ws;
  f16* xb    = (f16*)(ws);                       // 16,777,216 B
  f16* wkqvT = (f16*)(ws + 16777216);            //  6,291,456
  f16* wpT   = (f16*)(ws + 23068672);            //  2,097,152
  f16* qT    = (f16*)(ws + 25165824);            // 16,777,216
  f16* kT    = (f16*)(ws + 41943040);            // 16,777,216
  f16* vT    = (f16*)(ws + 58720256);            // 16,777,216
  f16* aout  = (f16*)(ws + 75497472);            // 16,777,216  -> ~92.3 MB

  cvt_kernel<<<8192, 256, 0, stream>>>(x, xb, (MM * CC) / 4);
  transpose_cvt<<<dim3(3 * CC / 32, CC / 32), dim3(32, 8), 0, stream>>>(w_kqv, wkqvT, CC, 3 * CC);
  transpose_cvt<<<dim3(CC / 32, CC / 32), dim3(32, 8), 0, stream>>>(w_proj, wpT, CC, CC);

  gemm_bt<0><<<dim3(3 * CC / 128, MM / 128), 256, 0, stream>>>(xb, wkqvT, qT, kT, vT, nullptr, nullptr);

  attn_kernel<<<dim3(BB * HH, 8), 512, 0, stream>>>(qT, kT, vT, aout);

  gemm_bt<1><<<dim3(CC / 128, MM / 128), 256, 0, stream>>>(aout, wpT, nullptr, nullptr, nullptr, b_proj, out);
}

// Round 27
// 179.674 us; speedup vs baseline: 1.0849x; 1.0813x over previous
//
#include <hip/hip_runtime.h>
#include <hip/hip_bf16.h>
#include <cstdint>

#define BB 4
#define TT 2048
#define CC 1024
#define HH 16
#define HS 64
#define MM (BB*TT)   // 8192

// scores computed in exp2 domain: fold 8 * log2(e) into Q once (QKV epilogue)
#define QSCALE 11.5415603629f

typedef _Float16 f16;
typedef _Float16 f16x8 __attribute__((ext_vector_type(8)));
typedef _Float16 f16x4 __attribute__((ext_vector_type(4)));
typedef float f32x4 __attribute__((ext_vector_type(4)));
typedef float f32x16 __attribute__((ext_vector_type(16)));

#define MFMA16(a,b,c) __builtin_amdgcn_mfma_f32_16x16x32_f16(a,b,c,0,0,0)
#define MFMA32(a,b,c) __builtin_amdgcn_mfma_f32_32x32x16_f16(a,b,c,0,0,0)

__device__ __forceinline__ void g2lds16(void* lds, const void* g) {
  __builtin_amdgcn_global_load_lds(
      (const __attribute__((address_space(1))) void*)g,
      (__attribute__((address_space(3))) void*)lds, 16, 0, 0);
}

__device__ __forceinline__ int pk2(float a, float b) {
  auto r = __builtin_amdgcn_cvt_pkrtz(a, b);   // __fp16 ext_vector(2)
  return __builtin_bit_cast(int, r);
}

union U8 { int4 i; f16x8 h; };

// ---------------- pre-pass: f32 -> f16 convert ----------------
__global__ __launch_bounds__(256) void cvt_kernel(const float* __restrict__ in,
                                                  f16* __restrict__ out, int n4) {
  int i = blockIdx.x * blockDim.x + threadIdx.x;
  if (i < n4) {
    float4 v = ((const float4*)in)[i];
    f16x4 o;
    o[0] = (f16)v.x; o[1] = (f16)v.y; o[2] = (f16)v.z; o[3] = (f16)v.w;
    ((f16x4*)out)[i] = o;
  }
}

// ---------------- pre-pass: transpose + convert: in[K][N] f32 -> out[N][K] f16
__global__ __launch_bounds__(256) void transpose_cvt(const float* __restrict__ in,
                                                     f16* __restrict__ out,
                                                     int K, int N) {
  __shared__ float tile[32][33];
  int n0 = blockIdx.x * 32, k0 = blockIdx.y * 32;
  int tx = threadIdx.x, ty = threadIdx.y;
  #pragma unroll
  for (int i = 0; i < 32; i += 8)
    tile[ty + i][tx] = in[(size_t)(k0 + ty + i) * N + n0 + tx];
  __syncthreads();
  #pragma unroll
  for (int i = 0; i < 32; i += 8)
    out[(size_t)(n0 + ty + i) * K + k0 + tx] = (f16)tile[tx][ty + i];
}

// ---------------- GEMM v10: m97 structure + row-panel XCD swizzle ----------
// 128x128 tile, 4 waves x 64x64 (acc[4][4]), SINGLE 32KB LDS buffer,
// plain __syncthreads. T1: XCD x owns row-panels by in [8x,8x+8) -> the 24
// (or NBX) blocks sharing an A panel land on ONE XCD; A working set 2MB
// fits its L2 -> stage A-loads become L2 hits (were 8x-overfetched HBM/L3).
// Flat grid, bijective: xcd = id&7, r = id>>3, by = xcd*8 + (r&7), bx = r>>3.
__device__ __forceinline__ void gstage(const f16* __restrict__ A,
                                       const f16* __restrict__ Bt,
                                       f16* as, f16* bs,
                                       int row0, int col0, int kt, int t) {
  const int K = 1024;
  #pragma unroll
  for (int i = 0; i < 4; ++i) {
    int off = i * 4096 + t * 16;        // byte offset in 16KB tile
    int row = off >> 7;                 // 128B per row
    int cbB = off & 127;
    int scb = cbB ^ ((row & 7) << 4);   // pre-swizzled source byte col
    g2lds16((char*)as + off, (const char*)(A  + (size_t)(row0 + row) * K + kt) + scb);
    g2lds16((char*)bs + off, (const char*)(Bt + (size_t)(col0 + row) * K + kt) + scb);
  }
}

template<int EPI, int NBX>
__global__ __launch_bounds__(256) void gemm_bt(const f16* __restrict__ A,
                                               const f16* __restrict__ Bt,
                                               f16* __restrict__ qT,
                                               f16* __restrict__ kT,
                                               f16* __restrict__ vT,
                                               const float* __restrict__ bias,
                                               float* __restrict__ outF) {
  const int K = 1024;
  __shared__ f16 As[128 * 64];
  __shared__ f16 Bs[128 * 64];
  const int t = threadIdx.x;
  const int l = t & 63, w = t >> 6;     // 4 waves
  const int lr = l & 15, lh = l >> 4;
  const int d = blockIdx.x;
  const int xcd = d & 7, r = d >> 3;
  const int by = xcd * 8 + (r & 7);     // 64 row panels = 8 per XCD
  const int bx = r >> 3;                // 0..NBX-1
  const int row0 = by * 128, col0 = bx * 128;
  const int wr = (w >> 1) * 64, wc = (w & 1) * 64;
  const int sx = (lr & 7) << 4;         // read-side swizzle (row&7 == lr&7)

  f32x4 acc[4][4] = {};

  for (int kt = 0; kt < K; kt += 64) {
    gstage(A, Bt, As, Bs, row0, col0, kt, t);
    __syncthreads();                     // drains vmcnt: tile ready
    const char* as = (const char*)As;
    const char* bs = (const char*)Bs;
    __builtin_amdgcn_s_setprio(1);
    #pragma unroll
    for (int kk = 0; kk < 64; kk += 32) {
      f16x8 af[4], bfr[4];
      #pragma unroll
      for (int m = 0; m < 4; ++m)
        af[m]  = *(const f16x8*)(as + (wr + m * 16 + lr) * 128
                                    + ((kk * 2 + lh * 16) ^ sx));
      #pragma unroll
      for (int n = 0; n < 4; ++n)
        bfr[n] = *(const f16x8*)(bs + (wc + n * 16 + lr) * 128
                                    + ((kk * 2 + lh * 16) ^ sx));
      #pragma unroll
      for (int m = 0; m < 4; ++m)
        #pragma unroll
        for (int n = 0; n < 4; ++n)
          acc[m][n] = MFMA16(af[m], bfr[n], acc[m][n]);
    }
    __builtin_amdgcn_s_setprio(0);
    __syncthreads();                     // readers done before next overwrite
  }

  #pragma unroll
  for (int m = 0; m < 4; ++m) {
    #pragma unroll
    for (int n = 0; n < 4; ++n) {
      #pragma unroll
      for (int j = 0; j < 4; ++j) {
        float val = acc[m][n][j];
        int gr = row0 + wr + m * 16 + lh * 4 + j;   // M index
        int gc = col0 + wc + n * 16 + lr;           // N index
        if (EPI == 0) {
          int which = gc >> 10;          // 0=q 1=k 2=v
          int c = gc & 1023;
          int h = c >> 6, dd = c & 63;
          int b = gr >> 11, tt = gr & 2047;
          size_t bh = (size_t)(b * HH + h);
          if (which == 0)      qT[(bh * TT + tt) * HS + dd] = (f16)(val * QSCALE);
          else if (which == 1) kT[(bh * TT + tt) * HS + dd] = (f16)val;
          else                 vT[(bh * HS + dd) * TT + tt] = (f16)val;
        } else {
          outF[(size_t)gr * CC + gc] = val + bias[gc];
        }
      }
    }
  }
}

// ---------------- flash attention v9: step-split wave-sets (2x TLP) --------
template<bool MASKED>
__device__ __forceinline__ void step32L(
    int kglob, int qa, int l31, int hi,
    const f16* __restrict__ ks, const f16* __restrict__ vs, int kbs,
    const f16x8 (&qf)[4],
    float& m, f32x4& lv, f32x16& oA, f32x16& oB) {
  const int sx = (l31 & 7) << 4;               // row-XOR swizzle (row&7 == l31&7)
  const char* krow = (const char*)(ks + (kbs + l31) * 64);
  f32x16 sa = {}, sb = {};
  {
    f16x8 kf0 = *(const f16x8*)(krow + ((0 * 32 + hi * 16) ^ sx));
    f16x8 kf1 = *(const f16x8*)(krow + ((1 * 32 + hi * 16) ^ sx));
    f16x8 kf2 = *(const f16x8*)(krow + ((2 * 32 + hi * 16) ^ sx));
    f16x8 kf3 = *(const f16x8*)(krow + ((3 * 32 + hi * 16) ^ sx));
    sa = MFMA32(kf0, qf[0], sa);
    sb = MFMA32(kf2, qf[2], sb);
    sa = MFMA32(kf1, qf[1], sa);
    sb = MFMA32(kf3, qf[3], sb);
  }
  float p[16];
  #pragma unroll
  for (int r = 0; r < 16; ++r) {
    float sv = sa[r] + sb[r];
    if (MASKED) {
      int k = kglob + (r & 3) + 8 * (r >> 2) + 4 * hi;
      p[r] = (k <= qa) ? sv : -INFINITY;
    } else p[r] = sv;
  }
  float t0 = fmaxf(fmaxf(p[0], p[1]), fmaxf(p[2], p[3]));
  float t1 = fmaxf(fmaxf(p[4], p[5]), fmaxf(p[6], p[7]));
  float t2 = fmaxf(fmaxf(p[8], p[9]), fmaxf(p[10], p[11]));
  float t3 = fmaxf(fmaxf(p[12], p[13]), fmaxf(p[14], p[15]));
  float mx = fmaxf(fmaxf(t0, t1), fmaxf(t2, t3));
  if (__any(mx > m + 14.0f)) {                 // rare rescale path
    mx = fmaxf(mx, __shfl_xor(mx, 32));
    float mn = fmaxf(m, mx);
    float corr = __builtin_amdgcn_exp2f(m - mn);
    m = mn;
    #pragma unroll
    for (int r = 0; r < 4; ++r) lv[r] *= corr;
    #pragma unroll
    for (int r = 0; r < 16; ++r) { oA[r] *= corr; oB[r] *= corr; }
  }
  #pragma unroll
  for (int r = 0; r < 16; ++r) {
    p[r] = __builtin_amdgcn_exp2f(p[r] - m);   // bounded by 2^14 (f16-safe)
    lv[r & 3] += p[r];
  }
  // P -> f16 pairs; half-exchange via v_permlane32_swap_b32 (VALU pipe)
  int pkv[8];
  #pragma unroll
  for (int j = 0; j < 8; ++j) pkv[j] = pk2(p[2 * j], p[2 * j + 1]);
  int e0 = pkv[0], e2 = pkv[2];
  asm("v_permlane32_swap_b32 %0, %1" : "+v"(e0), "+v"(e2));
  int e1 = pkv[1], e3 = pkv[3];
  asm("v_permlane32_swap_b32 %0, %1" : "+v"(e1), "+v"(e3));
  int f0 = pkv[4], f2 = pkv[6];
  asm("v_permlane32_swap_b32 %0, %1" : "+v"(f0), "+v"(f2));
  int f1 = pkv[5], f3 = pkv[7];
  asm("v_permlane32_swap_b32 %0, %1" : "+v"(f1), "+v"(f3));
  U8 b0, b1;
  b0.i = (int4){ e0, e1, e2, e3 };
  b1.i = (int4){ f0, f1, f2, f3 };
  const char* vrow0 = (const char*)(vs + l31 * 64);
  const char* vrow1 = (const char*)(vs + (l31 + 32) * 64);
  const int kc0 = (kbs * 2 + hi * 16) ^ sx;
  const int kc1 = (kbs * 2 + hi * 16 + 32) ^ sx;
  f16x8 v00 = *(const f16x8*)(vrow0 + kc0);
  f16x8 v01 = *(const f16x8*)(vrow0 + kc1);
  f16x8 v10 = *(const f16x8*)(vrow1 + kc0);
  f16x8 v11 = *(const f16x8*)(vrow1 + kc1);
  oA = MFMA32(v00, b0.h, oA);
  oA = MFMA32(v01, b1.h, oA);
  oB = MFMA32(v10, b0.h, oB);
  oB = MFMA32(v11, b1.h, oB);
}

struct SmemU {
  union {
    f16 kv[2][2][4096];        // [buf][K=0/V=1][elem] = 32 KB staging
    float om[4][64][32];       // 32 KB merge-O overlay (staging drained)
  };
  float mls[4][64][2];         // 2 KB merge (m, lsum)
};

__device__ __forceinline__ void stage8(const f16* __restrict__ Kb,
                                       const f16* __restrict__ Vb,
                                       f16* ks, f16* vs,
                                       int kb, int w, int l) {
  int off = w * 1024 + l * 16;    // 8 waves cover the 8 KB tile
  int row = off >> 7;
  int cb  = off & 127;
  int scb = cb ^ ((row & 7) << 4);
  g2lds16((char*)ks + off, (const char*)(Kb + (size_t)(kb + row) * HS) + scb);
  g2lds16((char*)vs + off, (const char*)(Vb + (size_t)row * TT + kb) + scb);
}

// grid (64 bh, 8 pairs). Block: q-block (15-pr) then (pr) -> uniform 34 units.
__global__ __launch_bounds__(512) void attn_kernel(const f16* __restrict__ qT,
                                                   const f16* __restrict__ kT,
                                                   const f16* __restrict__ vT,
                                                   f16* __restrict__ aout) {
  const int bh = blockIdx.x;        // x-fastest: same-bh blocks on XCD bh%8
  const int pr = blockIdx.y;        // 0..7
  const int t = threadIdx.x, l = t & 63, w = t >> 6;   // w 0..7
  const int ws = w & 3;             // q-subtile (32 rows) within 128
  const int kh = w >> 2;            // step-set: 0 -> kb, 1 -> kb+32
  const int l31 = l & 31, hi = l >> 5;
  const f16* __restrict__ Qb = qT + (size_t)bh * TT * HS;
  const f16* __restrict__ Kb = kT + (size_t)bh * TT * HS;
  const f16* __restrict__ Vb = vT + (size_t)bh * HS * TT;
  const int b = bh >> 4, h = bh & 15;

  __shared__ SmemU S;
  const int swm = (l & 7) << 2;     // merge-O float4 XOR swizzle

  #pragma unroll
  for (int ph = 0; ph < 2; ++ph) {
    const int qb = ph ? pr : (15 - pr);   // heavy phase first
    const int q0w = qb * 128 + ws * 32;
    const int qa = q0w + l31;

    f16x8 qf[4];
    #pragma unroll
    for (int j = 0; j < 4; ++j)
      qf[j] = *(const f16x8*)&Qb[(size_t)qa * HS + 16 * j + hi * 8];

    float m = -INFINITY;
    f32x4 lv = {};
    f32x16 oA = {}, oB = {};

    const int nt = 2 * qb + 2;
    stage8(Kb, Vb, S.kv[0][0], S.kv[0][1], 0, w, l);
    __syncthreads();
    int buf = 0;
    for (int ti = 0; ti < nt; ++ti) {
      if (ti + 1 < nt)
        stage8(Kb, Vb, S.kv[buf ^ 1][0], S.kv[buf ^ 1][1], (ti + 1) * 64, w, l);
      const int kb = ti * 64;
      const f16* ks = S.kv[buf][0];
      const f16* vs = S.kv[buf][1];
      if (kh == 0) {                           // wave-uniform branches
        if (kb < q0w)
          step32L<false>(kb, qa, l31, hi, ks, vs, 0, qf, m, lv, oA, oB);
        else if (kb == q0w)
          step32L<true >(kb, qa, l31, hi, ks, vs, 0, qf, m, lv, oA, oB);
      } else {
        if (kb + 32 < q0w)
          step32L<false>(kb + 32, qa, l31, hi, ks, vs, 32, qf, m, lv, oA, oB);
        else if (kb + 32 == q0w)
          step32L<true >(kb + 32, qa, l31, hi, ks, vs, 32, qf, m, lv, oA, oB);
      }
      __syncthreads();
      buf ^= 1;
    }

    float lsum = (lv[0] + lv[1]) + (lv[2] + lv[3]);
    lsum += __shfl_xor(lsum, 32);

    // ---- exact 2-way merge across step-sets (w and w+4 share q-rows) ----
    if (kh == 1) {
      #pragma unroll
      for (int rb = 0; rb < 4; ++rb) {
        f32x4 va = { oA[rb*4+0], oA[rb*4+1], oA[rb*4+2], oA[rb*4+3] };
        f32x4 vb = { oB[rb*4+0], oB[rb*4+1], oB[rb*4+2], oB[rb*4+3] };
        *(f32x4*)&S.om[ws][l][(rb * 4) ^ swm]        = va;
        *(f32x4*)&S.om[ws][l][((4 + rb) * 4) ^ swm]  = vb;
      }
      S.mls[ws][l][0] = m;
      S.mls[ws][l][1] = lsum;
    }
    __syncthreads();
    if (kh == 0) {
      float mB = S.mls[ws][l][0], lB = S.mls[ws][l][1];
      float mS = fmaxf(fmaxf(m, mB), -3.0e38f);   // finite guard (empty set)
      float cA = __builtin_amdgcn_exp2f(m - mS);
      float cB = __builtin_amdgcn_exp2f(mB - mS);
      float li = 1.0f / (lsum * cA + lB * cB);
      float sA = cA * li, sB = cB * li;
      f16* orow = aout + (size_t)(b * TT + qa) * CC + h * HS;
      #pragma unroll
      for (int rq = 0; rq < 4; ++rq) {
        f32x4 obl = *(const f32x4*)&S.om[ws][l][(rq * 4) ^ swm];
        f32x4 obh = *(const f32x4*)&S.om[ws][l][((4 + rq) * 4) ^ swm];
        f16x4 o4a, o4b;
        #pragma unroll
        for (int j = 0; j < 4; ++j) {
          int r = rq * 4 + j;
          o4a[j] = (f16)(oA[r] * sA + obl[j] * sB);
          o4b[j] = (f16)(oB[r] * sA + obh[j] * sB);
        }
        int dA = 8 * rq + 4 * hi;
        *(f16x4*)&orow[dA]      = o4a;
        *(f16x4*)&orow[32 + dA] = o4b;
      }
    }
    __syncthreads();   // om overlays staging: next phase must wait
  }
}

// ---------------- launch ----------------
extern "C" void kernel_launch(void* const* d_in, const int* in_sizes, int n_in,
                              void* d_out, int out_size, void* d_ws, size_t ws_size,
                              hipStream_t stream) {
  const float* x      = (const float*)d_in[0];
  const float* w_kqv  = (const float*)d_in[1];
  const float* w_proj = (const float*)d_in[2];
  const float* b_proj = (const float*)d_in[3];
  float* out = (float*)d_out;

  char* ws = (char*)d_ws;
  f16* xb    = (f16*)(ws);                       // 16,777,216 B
  f16* wkqvT = (f16*)(ws + 16777216);            //  6,291,456
  f16* wpT   = (f16*)(ws + 23068672);            //  2,097,152
  f16* qT    = (f16*)(ws + 25165824);            // 16,777,216
  f16* kT    = (f16*)(ws + 41943040);            // 16,777,216
  f16* vT    = (f16*)(ws + 58720256);            // 16,777,216
  f16* aout  = (f16*)(ws + 75497472);            // 16,777,216  -> ~92.3 MB

  cvt_kernel<<<8192, 256, 0, stream>>>(x, xb, (MM * CC) / 4);
  transpose_cvt<<<dim3(3 * CC / 32, CC / 32), dim3(32, 8), 0, stream>>>(w_kqv, wkqvT, CC, 3 * CC);
  transpose_cvt<<<dim3(CC / 32, CC / 32), dim3(32, 8), 0, stream>>>(w_proj, wpT, CC, CC);

  // qkv: 64 row panels x 24 col blocks = 1536 (flat, row-panel XCD swizzle)
  gemm_bt<0, 24><<<1536, 256, 0, stream>>>(xb, wkqvT, qT, kT, vT, nullptr, nullptr);

  attn_kernel<<<dim3(BB * HH, 8), 512, 0, stream>>>(qT, kT, vT, aout);

  // proj: 64 row panels x 8 col blocks = 512
  gemm_bt<1, 8><<<512, 256, 0, stream>>>(aout, wpT, nullptr, nullptr, nullptr, b_proj, out);
}